// Round 2
// baseline (451.637 us; speedup 1.0000x reference)
//
#include <hip/hip_runtime.h>
#include <hip/hip_bf16.h>

typedef __bf16 bf16;
typedef __bf16 bf16x8 __attribute__((ext_vector_type(8)));
typedef float f32x4 __attribute__((ext_vector_type(4)));

#define MFMA16(A, B, C) __builtin_amdgcn_mfma_f32_16x16x32_bf16((A), (B), (C), 0, 0, 0)

// ---------------------------------------------------------------------------
// Input dtype detection. flag=1: inputs are fp32; flag=0: inputs are bf16.
// True bf16 weights satisfy |w| <= 0.094 (trunc normal, std 0.031). fp32 data
// reinterpreted as bf16 has mantissa fragments with random exponents -> some
// |v| >= 1 with probability 1 - 2^-32.
// ---------------------------------------------------------------------------
__global__ void detect_kernel(const void* w, int* flag) {
    const bf16* p = (const bf16*)w;
    int fp32 = 0;
    for (int i = 0; i < 64; ++i) {
        float v = (float)p[i];
        if (!(fabsf(v) < 1.0f)) fp32 = 1;  // NaN also lands here
    }
    *flag = fp32;
}

// fp32 -> bf16 conversion (no-op when inputs already bf16). n % 1024 == 0.
__global__ __launch_bounds__(256) void convert_kernel(const void* src, bf16* dst,
                                                      const int* flagp) {
    if (*flagp == 0) return;
    int i = (blockIdx.x * 256 + threadIdx.x) * 4;
    float4 v = *(const float4*)((const float*)src + i);
    bf16 o[4] = {(bf16)v.x, (bf16)v.y, (bf16)v.z, (bf16)v.w};
    *(uint2*)(dst + i) = *(uint2*)o;
}

// ---------------------------------------------------------------------------
// NT GEMM: C[M,N] = A[M,K] * W[N,K]^T, bf16 in, fp32 accumulate.
// 64x64 tile per block, 4 waves (2x2), each wave 32x32 via 2x2 MFMAs.
// MODE 0: C bf16 [M,N].  MODE 1: C bf16 transposed into [B, H*dk, S] (for V).
// MODE 2: final output -> fp32 or bf16 per flag.
// ---------------------------------------------------------------------------
template <int MODE>
__global__ __launch_bounds__(256) void gemm_nt(const void* rawA, const bf16* convA,
                                               const void* rawW, const bf16* convW,
                                               void* Cout, const int* flagp,
                                               int M, int N, int K) {
    __shared__ __attribute__((aligned(16))) bf16 lsA[64 * 64];
    __shared__ __attribute__((aligned(16))) bf16 lsB[64 * 64];
    const int flag = *flagp;
    const bf16* A = flag ? convA : (const bf16*)rawA;
    const bf16* W = flag ? convW : (const bf16*)rawW;

    const int t = threadIdx.x;
    const int m0 = blockIdx.y * 64;
    const int n0 = blockIdx.x * 64;
    const int w = t >> 6, lane = t & 63;
    const int wr = w >> 1, wc = w & 1;
    const int llo = lane & 15, quad = lane >> 4;

    f32x4 acc[2][2] = {};

    for (int k0 = 0; k0 < K; k0 += 64) {
#pragma unroll
        for (int i = 0; i < 2; ++i) {
            int idx = i * 256 + t;
            int row = idx >> 3, cs = (idx & 7) * 8;
            *(uint4*)&lsA[row * 64 + cs] =
                *(const uint4*)&A[(size_t)(m0 + row) * K + k0 + cs];
            *(uint4*)&lsB[row * 64 + cs] =
                *(const uint4*)&W[(size_t)(n0 + row) * K + k0 + cs];
        }
        __syncthreads();
#pragma unroll
        for (int kk = 0; kk < 64; kk += 32) {
            bf16x8 a0 = *(const bf16x8*)&lsA[(wr * 32 + llo) * 64 + kk + quad * 8];
            bf16x8 a1 = *(const bf16x8*)&lsA[(wr * 32 + 16 + llo) * 64 + kk + quad * 8];
            bf16x8 b0 = *(const bf16x8*)&lsB[(wc * 32 + llo) * 64 + kk + quad * 8];
            bf16x8 b1 = *(const bf16x8*)&lsB[(wc * 32 + 16 + llo) * 64 + kk + quad * 8];
            acc[0][0] = MFMA16(a0, b0, acc[0][0]);
            acc[0][1] = MFMA16(a0, b1, acc[0][1]);
            acc[1][0] = MFMA16(a1, b0, acc[1][0]);
            acc[1][1] = MFMA16(a1, b1, acc[1][1]);
        }
        __syncthreads();
    }

#pragma unroll
    for (int i = 0; i < 2; ++i)
#pragma unroll
        for (int j = 0; j < 2; ++j)
#pragma unroll
            for (int r = 0; r < 4; ++r) {
                int row = m0 + wr * 32 + i * 16 + quad * 4 + r;
                int col = n0 + wc * 32 + j * 16 + llo;
                float v = acc[i][j][r];
                if (MODE == 1) {
                    // row = b*2048 + s ; col = h*64 + d ; Vt[b][col][s]
                    int bb = row >> 11, s = row & 2047;
                    ((bf16*)Cout)[((size_t)bb * 1024 + col) * 2048 + s] = (bf16)v;
                } else if (MODE == 2) {
                    if (flag)
                        ((float*)Cout)[(size_t)row * N + col] = v;
                    else
                        ((bf16*)Cout)[(size_t)row * N + col] = (bf16)v;
                } else {
                    ((bf16*)Cout)[(size_t)row * N + col] = (bf16)v;
                }
            }
}

// ---------------------------------------------------------------------------
// In-place RoPE on Q and K, layout [B*S, H*dk] bf16. One thread per pair.
// ---------------------------------------------------------------------------
__global__ __launch_bounds__(256) void rope_kernel(bf16* __restrict__ Q,
                                                   bf16* __restrict__ Kt,
                                                   int total) {
    int id = blockIdx.x * 256 + threadIdx.x;
    bf16* P = (id < total) ? Q : Kt;
    int pid = (id < total) ? id : id - total;
    int row = pid >> 9;  // B*S rows, 512 pairs each
    int pr = pid & 511;
    int h = pr >> 5, p = pr & 31;
    int s = row & 2047;
    size_t base = (size_t)row * 1024 + h * 64 + 2 * p;
    float t1 = (float)P[base], t2 = (float)P[base + 1];
    float freq = exp2f((float)p * -0.41524101186092956f);  // 10000^(-p/32)
    float ang = (float)s * freq;
    float sn = sinf(ang), cs = cosf(ang);
    P[base] = (bf16)(t1 * cs - t2 * sn);
    P[base + 1] = (bf16)(t1 * sn + t2 * cs);
}

// ---------------------------------------------------------------------------
// Causal flash attention, 1 wave per (b, h, 16-query tile).
// Q,K layout [B*S, H*dk]; V transposed [B, H*dk, S]; out [B*S, H*dk] (bf16).
// ---------------------------------------------------------------------------
__global__ __launch_bounds__(64) void attn_kernel(const bf16* __restrict__ Q,
                                                  const bf16* __restrict__ Kr,
                                                  const bf16* __restrict__ Vt,
                                                  bf16* __restrict__ O) {
    __shared__ __attribute__((aligned(16))) bf16 lsP[16 * 32];
    const int blk = blockIdx.x;
    const int qt = blk & 127;
    const int bh = blk >> 7;
    const int b = bh >> 4, h = bh & 15;
    const int lane = threadIdx.x;
    const int llo = lane & 15, quad = lane >> 4;
    const int q0 = qt * 16;

    const size_t qbase = ((size_t)(b * 2048 + q0 + llo)) * 1024 + h * 64 + quad * 8;
    bf16x8 aQ0 = *(const bf16x8*)&Q[qbase];
    bf16x8 aQ1 = *(const bf16x8*)&Q[qbase + 32];

    f32x4 o[4] = {};
    float mI[4], lI[4];
#pragma unroll
    for (int r = 0; r < 4; ++r) {
        mI[r] = -INFINITY;
        lI[r] = 0.f;
    }

    const int ntiles = (q0 + 16 + 31) >> 5;
    const int qrow = q0 + quad * 4;  // + r

    for (int t = 0; t < ntiles; ++t) {
        const int kv0 = t * 32;
        f32x4 s[2];
#pragma unroll
        for (int half = 0; half < 2; ++half) {
            const size_t kb =
                ((size_t)(b * 2048 + kv0 + half * 16 + llo)) * 1024 + h * 64 + quad * 8;
            bf16x8 k0 = *(const bf16x8*)&Kr[kb];
            bf16x8 k1 = *(const bf16x8*)&Kr[kb + 32];
            f32x4 z = {};
            z = MFMA16(aQ0, k0, z);
            z = MFMA16(aQ1, k1, z);
            s[half] = z;
        }
#pragma unroll
        for (int half = 0; half < 2; ++half) {
            int kv = kv0 + half * 16 + llo;
#pragma unroll
            for (int r = 0; r < 4; ++r) {
                float v = s[half][r] * 0.125f;
                s[half][r] = (kv <= qrow + r) ? v : -INFINITY;
            }
        }
        float alpha[4];
#pragma unroll
        for (int r = 0; r < 4; ++r) {
            float mr = fmaxf(s[0][r], s[1][r]);
#pragma unroll
            for (int off = 1; off < 16; off <<= 1) mr = fmaxf(mr, __shfl_xor(mr, off));
            float mn = fmaxf(mI[r], mr);
            alpha[r] = __expf(mI[r] - mn);
            mI[r] = mn;
        }
        float rs[4];
#pragma unroll
        for (int r = 0; r < 4; ++r) {
            float p0 = __expf(s[0][r] - mI[r]);
            float p1 = __expf(s[1][r] - mI[r]);
            rs[r] = p0 + p1;
            lsP[(quad * 4 + r) * 32 + llo] = (bf16)p0;
            lsP[(quad * 4 + r) * 32 + 16 + llo] = (bf16)p1;
        }
#pragma unroll
        for (int r = 0; r < 4; ++r) {
            float v = rs[r];
#pragma unroll
            for (int off = 1; off < 16; off <<= 1) v += __shfl_xor(v, off);
            lI[r] = lI[r] * alpha[r] + v;
            o[0][r] *= alpha[r];
            o[1][r] *= alpha[r];
            o[2][r] *= alpha[r];
            o[3][r] *= alpha[r];
        }
        __syncthreads();
        bf16x8 aP = *(const bf16x8*)&lsP[llo * 32 + quad * 8];
#pragma unroll
        for (int g = 0; g < 4; ++g) {
            const size_t vb =
                ((size_t)(b * 1024 + h * 64 + g * 16 + llo)) * 2048 + kv0 + quad * 8;
            bf16x8 bV = *(const bf16x8*)&Vt[vb];
            o[g] = MFMA16(aP, bV, o[g]);
        }
        __syncthreads();
    }

#pragma unroll
    for (int r = 0; r < 4; ++r) {
        float inv = 1.f / lI[r];
        size_t ob = ((size_t)(b * 2048 + q0 + quad * 4 + r)) * 1024 + h * 64;
#pragma unroll
        for (int g = 0; g < 4; ++g) {
            O[ob + g * 16 + llo] = (bf16)(o[g][r] * inv);
        }
    }
}

// ---------------------------------------------------------------------------
extern "C" void kernel_launch(void* const* d_in, const int* in_sizes, int n_in,
                              void* d_out, int out_size, void* d_ws, size_t ws_size,
                              hipStream_t stream) {
    const int M = 4096, N = 1024, K = 1024;  // B*S = 4096, D = 1024
    const size_t TN = (size_t)M * N;         // 4M elements

    int* flag = (int*)d_ws;
    bf16* Q = (bf16*)((char*)d_ws + 256);  // [4096,1024]
    bf16* Kb = Q + TN;                     // [4096,1024]
    bf16* Vt = Kb + TN;                    // [B,1024,2048] transposed
    bf16* xb = Vt + TN;                    // bf16 copy of x (fp32 case only)
    bf16* Wb0 = xb + TN;                   // bf16 copies of weights
    bf16* Wb1 = Wb0 + (size_t)N * K;
    bf16* Wb2 = Wb1 + (size_t)N * K;
    bf16* Wb3 = Wb2 + (size_t)N * K;
    bf16* AO = Q;  // attention output aliases Q (safe: per-block private slice)

    detect_kernel<<<1, 1, 0, stream>>>(d_in[1], flag);
    convert_kernel<<<4096, 256, 0, stream>>>(d_in[0], xb, flag);
    convert_kernel<<<1024, 256, 0, stream>>>(d_in[1], Wb0, flag);
    convert_kernel<<<1024, 256, 0, stream>>>(d_in[2], Wb1, flag);
    convert_kernel<<<1024, 256, 0, stream>>>(d_in[3], Wb2, flag);
    convert_kernel<<<1024, 256, 0, stream>>>(d_in[4], Wb3, flag);

    dim3 g(N / 64, M / 64), blk(256);
    gemm_nt<0><<<g, blk, 0, stream>>>(d_in[0], xb, d_in[1], Wb0, Q, flag, M, N, K);
    gemm_nt<0><<<g, blk, 0, stream>>>(d_in[0], xb, d_in[2], Wb1, Kb, flag, M, N, K);
    gemm_nt<1><<<g, blk, 0, stream>>>(d_in[0], xb, d_in[3], Wb2, Vt, flag, M, N, K);

    const int total = 4096 * 512;  // rope pairs per tensor
    rope_kernel<<<(2 * total) / 256, 256, 0, stream>>>(Q, Kb, total);

    attn_kernel<<<4096, 64, 0, stream>>>(Q, Kb, Vt, AO);

    gemm_nt<2><<<g, blk, 0, stream>>>(AO, AO, d_in[4], Wb3, d_out, flag, M, N, K);
}

// Round 3
// 307.368 us; speedup vs baseline: 1.4694x; 1.4694x over previous
//
#include <hip/hip_runtime.h>
#include <hip/hip_bf16.h>

typedef __bf16 bf16;
typedef __bf16 bf16x8 __attribute__((ext_vector_type(8)));
typedef float f32x4 __attribute__((ext_vector_type(4)));

#define MFMA16(A, B, C) __builtin_amdgcn_mfma_f32_16x16x32_bf16((A), (B), (C), 0, 0, 0)

static __device__ __forceinline__ void gload16(const bf16* g, bf16* l) {
    __builtin_amdgcn_global_load_lds((const __attribute__((address_space(1))) void*)g,
                                     (__attribute__((address_space(3))) void*)l, 16, 0, 0);
}

// ---------------------------------------------------------------------------
// Input dtype detection. flag=1: inputs are fp32; flag=0: bf16.
// ---------------------------------------------------------------------------
__global__ void detect_kernel(const void* w, int* flag) {
    const bf16* p = (const bf16*)w;
    int fp32 = 0;
    for (int i = 0; i < 64; ++i) {
        float v = (float)p[i];
        if (!(fabsf(v) < 1.0f)) fp32 = 1;  // NaN lands here too
    }
    *flag = fp32;
}

// fp32 -> bf16 conversion (no-op when inputs already bf16).
__global__ __launch_bounds__(256) void convert_kernel(const void* src, bf16* dst,
                                                      const int* flagp) {
    if (*flagp == 0) return;
    int i = (blockIdx.x * 256 + threadIdx.x) * 4;
    float4 v = *(const float4*)((const float*)src + i);
    bf16 o[4] = {(bf16)v.x, (bf16)v.y, (bf16)v.z, (bf16)v.w};
    *(uint2*)(dst + i) = *(uint2*)o;
}

// ---------------------------------------------------------------------------
// NT GEMM: C[M,N] = A[M,K] * W[N,K]^T, bf16 in, fp32 accumulate.
// 128x64 tile, 4 waves (2x2), wave = 64x32 via 4x2 MFMAs, BK=64.
// global_load_lds(16B) staging; XOR chunk swizzle kills b128 bank conflicts.
// MODE 0: C bf16 [M,N].  MODE 1: C bf16 transposed -> [B, H*dk, S] (for V).
// MODE 2: final output -> fp32 or bf16 per flag.
// ---------------------------------------------------------------------------
template <int MODE>
__global__ __launch_bounds__(256) void gemm_nt(const void* rawA, const bf16* convA,
                                               const void* rawW, const bf16* convW,
                                               void* Cout, const int* flagp,
                                               int M, int N, int K) {
    __shared__ __attribute__((aligned(16))) bf16 lsA[128 * 64];
    __shared__ __attribute__((aligned(16))) bf16 lsB[64 * 64];
    const int flag = *flagp;
    const bf16* A = flag ? convA : (const bf16*)rawA;
    const bf16* W = flag ? convW : (const bf16*)rawW;

    const int t = threadIdx.x;
    const int m0 = blockIdx.y * 128;
    const int n0 = blockIdx.x * 64;
    const int w = t >> 6, lane = t & 63;
    const int wr = w >> 1, wc = w & 1;
    const int llo = lane & 15, quad = lane >> 4;

    // staging: thread t covers row (i*32 + t>>3), swizzled 16B chunk
    const int srow = t >> 3;
    const int sg = (t & 7) ^ (srow & 7);  // global chunk fetched into slot t&7
    const bf16* Abase = A + (size_t)(m0 + srow) * K + sg * 8;
    const bf16* Wbase = W + (size_t)(n0 + srow) * K + sg * 8;
    bf16* lA = &lsA[t * 8];
    bf16* lB = &lsB[t * 8];

    f32x4 acc[4][2] = {};

    for (int k0 = 0; k0 < K; k0 += 64) {
#pragma unroll
        for (int i = 0; i < 4; ++i)
            gload16(Abase + (size_t)i * 32 * K + k0, lA + i * 2048);
#pragma unroll
        for (int i = 0; i < 2; ++i)
            gload16(Wbase + (size_t)i * 32 * K + k0, lB + i * 2048);
        __syncthreads();  // drains vmcnt -> LDS visible
#pragma unroll
        for (int kc = 0; kc < 2; ++kc) {
            bf16x8 a[4], bb[2];
            const int g = kc * 4 + quad;
#pragma unroll
            for (int mi = 0; mi < 4; ++mi) {
                int row = wr * 64 + mi * 16 + llo;
                a[mi] = *(const bf16x8*)&lsA[row * 64 + ((g ^ (row & 7)) * 8)];
            }
#pragma unroll
            for (int ni = 0; ni < 2; ++ni) {
                int row = wc * 32 + ni * 16 + llo;
                bb[ni] = *(const bf16x8*)&lsB[row * 64 + ((g ^ (row & 7)) * 8)];
            }
#pragma unroll
            for (int mi = 0; mi < 4; ++mi)
#pragma unroll
                for (int ni = 0; ni < 2; ++ni)
                    acc[mi][ni] = MFMA16(a[mi], bb[ni], acc[mi][ni]);
        }
        __syncthreads();
    }

#pragma unroll
    for (int mi = 0; mi < 4; ++mi)
#pragma unroll
        for (int ni = 0; ni < 2; ++ni)
#pragma unroll
            for (int r = 0; r < 4; ++r) {
                int row = m0 + wr * 64 + mi * 16 + quad * 4 + r;
                int col = n0 + wc * 32 + ni * 16 + llo;
                float v = acc[mi][ni][r];
                if (MODE == 1) {
                    int b = row >> 11, s = row & 2047;
                    ((bf16*)Cout)[((size_t)b * 1024 + col) * 2048 + s] = (bf16)v;
                } else if (MODE == 2) {
                    if (flag)
                        ((float*)Cout)[(size_t)row * N + col] = v;
                    else
                        ((bf16*)Cout)[(size_t)row * N + col] = (bf16)v;
                } else {
                    ((bf16*)Cout)[(size_t)row * N + col] = (bf16)v;
                }
            }
}

// ---------------------------------------------------------------------------
// In-place RoPE on Q and K, layout [B*S, H*dk] bf16.
// ---------------------------------------------------------------------------
__global__ __launch_bounds__(256) void rope_kernel(bf16* __restrict__ Q,
                                                   bf16* __restrict__ Kt,
                                                   int total) {
    int id = blockIdx.x * 256 + threadIdx.x;
    bf16* P = (id < total) ? Q : Kt;
    int pid = (id < total) ? id : id - total;
    int row = pid >> 9;
    int pr = pid & 511;
    int h = pr >> 5, p = pr & 31;
    int s = row & 2047;
    size_t base = (size_t)row * 1024 + h * 64 + 2 * p;
    float t1 = (float)P[base], t2 = (float)P[base + 1];
    float freq = exp2f((float)p * -0.41524101186092956f);  // 10000^(-p/32)
    float ang = (float)s * freq;
    float sn = sinf(ang), cs = cosf(ang);
    P[base] = (bf16)(t1 * cs - t2 * sn);
    P[base + 1] = (bf16)(t1 * sn + t2 * cs);
}

// ---------------------------------------------------------------------------
// Causal flash attention v2: 1 wave per (b, h, 16-query tile), kv-chunk 64,
// NO barriers (single wave; DS ops complete in order) -> loads pipeline
// across chunks. Heavy q-tiles dispatched first (reversed qt).
// ---------------------------------------------------------------------------
__global__ __launch_bounds__(64) void attn_kernel(const bf16* __restrict__ Q,
                                                  const bf16* __restrict__ Kr,
                                                  const bf16* __restrict__ Vt,
                                                  bf16* __restrict__ O) {
    __shared__ __attribute__((aligned(16))) bf16 lsP[16 * 72];  // pad: 72 elem stride
    const int blk = blockIdx.x;
    const int qt = 127 - (blk >> 5);  // heavy tiles first
    const int bh = blk & 31;
    const int b = bh >> 4, h = bh & 15;
    const int lane = threadIdx.x;
    const int llo = lane & 15, quad = lane >> 4;
    const int q0 = qt * 16;

    const size_t qbase = ((size_t)(b * 2048 + q0 + llo)) * 1024 + h * 64 + quad * 8;
    bf16x8 aQ0 = *(const bf16x8*)&Q[qbase];
    bf16x8 aQ1 = *(const bf16x8*)&Q[qbase + 32];

    f32x4 o[4] = {};
    float mI[4], lI[4];
#pragma unroll
    for (int r = 0; r < 4; ++r) {
        mI[r] = -INFINITY;
        lI[r] = 0.f;
    }

    const int ntiles = (q0 + 16 + 63) >> 6;
    const int qrow = q0 + quad * 4;  // + r
    const size_t kbase = (size_t)(b * 2048) * 1024 + h * 64 + quad * 8;
    const size_t vbase = (size_t)(b * 1024 + h * 64) * 2048 + quad * 8;

    for (int t = 0; t < ntiles; ++t) {
        const int kv0 = t << 6;
        f32x4 s[4];
#pragma unroll
        for (int half = 0; half < 4; ++half) {
            const size_t kb = kbase + (size_t)(kv0 + half * 16 + llo) * 1024;
            bf16x8 k0 = *(const bf16x8*)&Kr[kb];
            bf16x8 k1 = *(const bf16x8*)&Kr[kb + 32];
            f32x4 z = {};
            z = MFMA16(aQ0, k0, z);
            z = MFMA16(aQ1, k1, z);
            s[half] = z;
        }
#pragma unroll
        for (int half = 0; half < 4; ++half) {
            int kv = kv0 + half * 16 + llo;
#pragma unroll
            for (int r = 0; r < 4; ++r) {
                float v = s[half][r] * 0.125f;
                s[half][r] = (kv <= qrow + r) ? v : -INFINITY;
            }
        }
        float alpha[4];
#pragma unroll
        for (int r = 0; r < 4; ++r) {
            float mr = fmaxf(fmaxf(s[0][r], s[1][r]), fmaxf(s[2][r], s[3][r]));
#pragma unroll
            for (int off = 1; off < 16; off <<= 1) mr = fmaxf(mr, __shfl_xor(mr, off));
            float mn = fmaxf(mI[r], mr);
            alpha[r] = __expf(mI[r] - mn);
            mI[r] = mn;
        }
#pragma unroll
        for (int r = 0; r < 4; ++r) {
            float rsum = 0.f;
#pragma unroll
            for (int half = 0; half < 4; ++half) {
                float p = __expf(s[half][r] - mI[r]);
                rsum += p;
                lsP[(quad * 4 + r) * 72 + half * 16 + llo] = (bf16)p;
            }
#pragma unroll
            for (int off = 1; off < 16; off <<= 1) rsum += __shfl_xor(rsum, off);
            lI[r] = lI[r] * alpha[r] + rsum;
            o[0][r] *= alpha[r];
            o[1][r] *= alpha[r];
            o[2][r] *= alpha[r];
            o[3][r] *= alpha[r];
        }
        __builtin_amdgcn_wave_barrier();  // order DS write -> DS read (same wave, in-order LDS)
#pragma unroll
        for (int kc = 0; kc < 2; ++kc) {
            bf16x8 aP = *(const bf16x8*)&lsP[llo * 72 + kc * 32 + quad * 8];
#pragma unroll
            for (int g = 0; g < 4; ++g) {
                bf16x8 bV = *(const bf16x8*)&Vt[vbase + (size_t)(g * 16 + llo) * 2048 +
                                                kv0 + kc * 32];
                o[g] = MFMA16(aP, bV, o[g]);
            }
        }
        __builtin_amdgcn_wave_barrier();  // order DS reads before next chunk's writes
    }

#pragma unroll
    for (int r = 0; r < 4; ++r) {
        float inv = 1.f / lI[r];
        size_t ob = ((size_t)(b * 2048 + q0 + quad * 4 + r)) * 1024 + h * 64;
#pragma unroll
        for (int g = 0; g < 4; ++g) {
            O[ob + g * 16 + llo] = (bf16)(o[g][r] * inv);
        }
    }
}

// ---------------------------------------------------------------------------
extern "C" void kernel_launch(void* const* d_in, const int* in_sizes, int n_in,
                              void* d_out, int out_size, void* d_ws, size_t ws_size,
                              hipStream_t stream) {
    const int M = 4096, N = 1024, K = 1024;  // B*S = 4096, D = 1024
    const size_t TN = (size_t)M * N;

    int* flag = (int*)d_ws;
    bf16* Q = (bf16*)((char*)d_ws + 256);
    bf16* Kb = Q + TN;
    bf16* Vt = Kb + TN;   // [B, H*dk, S] transposed
    bf16* xb = Vt + TN;   // bf16 copy of x (fp32 case)
    bf16* Wb0 = xb + TN;
    bf16* Wb1 = Wb0 + (size_t)N * K;
    bf16* Wb2 = Wb1 + (size_t)N * K;
    bf16* Wb3 = Wb2 + (size_t)N * K;
    bf16* AO = Q;  // attention output aliases Q (per-block private slice)

    detect_kernel<<<1, 1, 0, stream>>>(d_in[1], flag);
    convert_kernel<<<4096, 256, 0, stream>>>(d_in[0], xb, flag);
    convert_kernel<<<1024, 256, 0, stream>>>(d_in[1], Wb0, flag);
    convert_kernel<<<1024, 256, 0, stream>>>(d_in[2], Wb1, flag);
    convert_kernel<<<1024, 256, 0, stream>>>(d_in[3], Wb2, flag);
    convert_kernel<<<1024, 256, 0, stream>>>(d_in[4], Wb3, flag);

    dim3 g(N / 64, M / 128), blk(256);
    gemm_nt<0><<<g, blk, 0, stream>>>(d_in[0], xb, d_in[1], Wb0, Q, flag, M, N, K);
    gemm_nt<0><<<g, blk, 0, stream>>>(d_in[0], xb, d_in[2], Wb1, Kb, flag, M, N, K);
    gemm_nt<1><<<g, blk, 0, stream>>>(d_in[0], xb, d_in[3], Wb2, Vt, flag, M, N, K);

    const int total = 4096 * 512;
    rope_kernel<<<(2 * total) / 256, 256, 0, stream>>>(Q, Kb, total);

    attn_kernel<<<4096, 64, 0, stream>>>(Q, Kb, Vt, AO);

    gemm_nt<2><<<g, blk, 0, stream>>>(AO, AO, d_in[4], Wb3, d_out, flag, M, N, K);
}